// Round 3
// baseline (293.158 us; speedup 1.0000x reference)
//
#include <hip/hip_runtime.h>
#include <stdint.h>

#define BDIM 4
#define CDIM 128
#define NDIM 4096
#define KSEL 10

typedef unsigned long long ull;

// CK-style global->LDS direct copy (16 B/lane).
__device__ __forceinline__ void async_cp16(void* lds, const void* g) {
  auto* gp = (const __attribute__((address_space(1))) unsigned int*)(uintptr_t)g;
  auto* lp = (__attribute__((address_space(3))) unsigned int*)(unsigned int)(uintptr_t)lds;
  __builtin_amdgcn_global_load_lds(gp, lp, 16, 0, 0);
}

__device__ __forceinline__ ull umax64(ull a, ull b) { return a > b ? a : b; }
__device__ __forceinline__ ull umin64(ull a, ull b) { return a > b ? b : a; }

// merge two sorted-desc pairs (a0>=a1),(b0>=b1) -> sorted top-2 of union
__device__ __forceinline__ void merge2(ull& a0, ull& a1, ull b0, ull b1) {
  ull c0 = umax64(a0, b0);
  ull c1 = umax64(umin64(a0, b0), umax64(a1, b1));
  a0 = c0; a1 = c1;
}

__device__ __forceinline__ ull makekey(float s, unsigned low) {
  unsigned u = __float_as_uint(s);
  unsigned mono = u ^ ((unsigned)(((int)u) >> 31) | 0x80000000u);
  return ((ull)mono << 32) | (ull)low;
}

// ---------------------------------------------------------------------------
// Kernel A: xx[b][n] = sum_c x[b][c][n]^2
// ---------------------------------------------------------------------------
__global__ __launch_bounds__(256) void xx_kernel(const float* __restrict__ x,
                                                 float* __restrict__ xx) {
  int t = threadIdx.x;
  int nl = t >> 2;
  int part = t & 3;
  int g = blockIdx.x * 64 + nl;
  int b = g >> 12;
  int n = g & (NDIM - 1);
  const float* xp = x + (size_t)b * CDIM * NDIM + n;
  float s = 0.f;
  int c0 = part * 32;
#pragma unroll
  for (int i = 0; i < 32; ++i) {
    float v = xp[(size_t)(c0 + i) * NDIM];
    s += v * v;
  }
  s += __shfl_xor(s, 1, 4);
  s += __shfl_xor(s, 2, 4);
  if (part == 0) xx[g] = s;
}

// ---------------------------------------------------------------------------
// Kernel W: WT[c][o] = W[o][c]
// ---------------------------------------------------------------------------
__global__ __launch_bounds__(256) void wtrans_kernel(const float* __restrict__ W,
                                                     float* __restrict__ WT) {
  int c = blockIdx.x, o = threadIdx.x;
  WT[c * 256 + o] = W[o * 256 + c];
}

// ---------------------------------------------------------------------------
// Kernel S: score GEMM (symmetry-halved) -> per-(row, 64-col-group) top-2
// candidate keys. NO sc matrix. pc[row][64][2] u64 per batch (4 MB vs 64 MB).
// Key = mono(score)<<32 | (4095-m): (val desc, idx asc) exact order.
// R11: __launch_bounds__(256,4) relaxes the VGPR cap 64->128. R10's
// double-buffer null-result showed staging latency is hidden; the remaining
// 31% idle is per-wave dependency stalls at ~2.75 resident waves/SIMD. With
// 64 VGPRs the compiler can't keep ds_read_b128 results in flight across the
// FMA stream (4 float4 = 16 VGPR in flight). 128-VGPR budget + unroll-8 lets
// it pipeline LDS reads ~2 cc-steps deep. 16-wave/CU cap > measured 11, so
// no residency loss. Numerics bit-identical (same fmaf chain order).
// ---------------------------------------------------------------------------
__global__ __launch_bounds__(256, 4) void score_kernel(const float* __restrict__ x,
                                                       const float* __restrict__ xxg,
                                                       ull* __restrict__ pcall) {
  const int N = NDIM;
  int bb = blockIdx.y;
  ull* pcb = pcall + (size_t)bb * N * 128;
  int p = blockIdx.x;
  int I = 0;
  while (p >= 32 - I) { p -= 32 - I; ++I; }
  int J = I + p;
  int n0 = I * 128, m0 = J * 128;

  int t = threadIdx.x;
  int tx = t & 15, ty = t >> 4;
  int tx4 = tx * 4, ty4 = ty * 4;

  // 2 buffers x (xn[16][128] + xm[16][128]) = 8192 floats = 32 KB.
  // Also reused as merge scratch (16 KB) after the GEMM.
  __shared__ float smem[8192];

  const float* xb = x + (size_t)bb * CDIM * N;

  float acc[8][8];
#pragma unroll
  for (int i = 0; i < 8; ++i)
#pragma unroll
    for (int j = 0; j < 8; ++j) acc[i][j] = 0.f;

  // stage 16-channel chunk ch into buffer buf (xn at buf, xm at buf+2048)
  auto stage = [&](float* buf, int ch) {
    int c0 = ch * 16;
#pragma unroll
    for (int pp = 0; pp < 2; ++pp) {
      int i4 = t + 256 * pp;
      async_cp16(&buf[i4 * 4], &xb[(size_t)(c0 + (i4 >> 5)) * N + n0 + (i4 & 31) * 4]);
    }
#pragma unroll
    for (int pp = 0; pp < 2; ++pp) {
      int i4 = t + 256 * pp;
      async_cp16(&buf[2048 + i4 * 4], &xb[(size_t)(c0 + (i4 >> 5)) * N + m0 + (i4 & 31) * 4]);
    }
  };

  stage(smem, 0);  // prologue prefetch (chunk 0 -> buf 0)

  for (int ch = 0; ch < 8; ++ch) {
    // Drains this wave's stage(ch) loads (the only outstanding VMEM) and
    // ensures all waves finished compute(ch-1) before buf[ch+1&1] is rewritten.
    __syncthreads();
    float* cur = smem + (ch & 1) * 4096;
    if (ch < 7) stage(smem + ((ch + 1) & 1) * 4096, ch + 1);

    float* xn_s = cur;
    float* xm_s = cur + 2048;
#pragma unroll 8
    for (int cc = 0; cc < 16; ++cc) {
      float4 a0 = *(const float4*)&xn_s[cc * 128 + ty4];
      float4 a1 = *(const float4*)&xn_s[cc * 128 + ty4 + 64];
      float4 b0 = *(const float4*)&xm_s[cc * 128 + tx4];
      float4 b1 = *(const float4*)&xm_s[cc * 128 + tx4 + 64];
      float av[8] = {a0.x, a0.y, a0.z, a0.w, a1.x, a1.y, a1.z, a1.w};
      float bv[8] = {b0.x, b0.y, b0.z, b0.w, b1.x, b1.y, b1.z, b1.w};
#pragma unroll
      for (int i = 0; i < 8; ++i)
#pragma unroll
        for (int j = 0; j < 8; ++j) acc[i][j] += av[i] * bv[j];
    }
  }

  const float* xxb = xxg + (size_t)bb * N;

  // ----- n-side: rows n0.., groups 2J,2J+1 -----
  {
    float4 w0 = *(const float4*)&xxb[m0 + tx4];
    float4 w1 = *(const float4*)&xxb[m0 + tx4 + 64];
    float xv[8] = {w0.x, w0.y, w0.z, w0.w, w1.x, w1.y, w1.z, w1.w};
    unsigned mlow[8];
#pragma unroll
    for (int j = 0; j < 8; ++j)
      mlow[j] = 4095u - (unsigned)(m0 + tx4 + (j & 3) + (j >> 2) * 64);
#pragma unroll
    for (int i = 0; i < 8; ++i) {
      ull k[8];
#pragma unroll
      for (int j = 0; j < 8; ++j)
        k[j] = makekey(__builtin_fmaf(2.f, acc[i][j], -xv[j]), mlow[j]);
      ull g0a = umax64(k[0], k[1]), g0b = umin64(k[0], k[1]);
      merge2(g0a, g0b, umax64(k[2], k[3]), umin64(k[2], k[3]));
      ull g1a = umax64(k[4], k[5]), g1b = umin64(k[4], k[5]);
      merge2(g1a, g1b, umax64(k[6], k[7]), umin64(k[6], k[7]));
#pragma unroll
      for (int off = 1; off < 16; off <<= 1) {
        ull p0 = __shfl_xor(g0a, off), p1 = __shfl_xor(g0b, off);
        merge2(g0a, g0b, p0, p1);
        ull q0 = __shfl_xor(g1a, off), q1 = __shfl_xor(g1b, off);
        merge2(g1a, g1b, q0, q1);
      }
      if (tx == 0) {
        int row = n0 + ty4 + (i & 3) + (i >> 2) * 64;
        ull* pr = pcb + (size_t)row * 128;
        ulonglong2 v0; v0.x = g0a; v0.y = g0b;
        ulonglong2 v1; v1.x = g1a; v1.y = g1b;
        *(ulonglong2*)&pr[(2 * J) * 2] = v0;
        *(ulonglong2*)&pr[(2 * J + 1) * 2] = v1;
      }
    }
  }

  // ----- m-side (off-diag): rows m0.., groups 2I,2I+1 -----
  if (J != I) {
    __syncthreads();  // GEMM LDS reads done; reuse smem for merge scratch
    ull* lm = (ull*)smem;  // [128 lr][4 wave][2 g][2] = 2048 u64 = 16 KB
    float4 u0 = *(const float4*)&xxb[n0 + ty4];
    float4 u1 = *(const float4*)&xxb[n0 + ty4 + 64];
    float uv[8] = {u0.x, u0.y, u0.z, u0.w, u1.x, u1.y, u1.z, u1.w};
    unsigned nlow[8];
#pragma unroll
    for (int i = 0; i < 8; ++i)
      nlow[i] = 4095u - (unsigned)(n0 + ty4 + (i & 3) + (i >> 2) * 64);
    int wv = t >> 6;
#pragma unroll
    for (int j = 0; j < 8; ++j) {
      ull k[8];
#pragma unroll
      for (int i = 0; i < 8; ++i)
        k[i] = makekey(__builtin_fmaf(2.f, acc[i][j], -uv[i]), nlow[i]);
      ull g0a = umax64(k[0], k[1]), g0b = umin64(k[0], k[1]);
      merge2(g0a, g0b, umax64(k[2], k[3]), umin64(k[2], k[3]));
      ull g1a = umax64(k[4], k[5]), g1b = umin64(k[4], k[5]);
      merge2(g1a, g1b, umax64(k[6], k[7]), umin64(k[6], k[7]));
#pragma unroll
      for (int off = 16; off < 64; off <<= 1) {
        ull p0 = __shfl_xor(g0a, off), p1 = __shfl_xor(g0b, off);
        merge2(g0a, g0b, p0, p1);
        ull q0 = __shfl_xor(g1a, off), q1 = __shfl_xor(g1b, off);
        merge2(g1a, g1b, q0, q1);
      }
      if ((ty & 3) == 0) {
        int lr = tx4 + (j & 3) + (j >> 2) * 64;
        lm[lr * 16 + wv * 4 + 0] = g0a;
        lm[lr * 16 + wv * 4 + 1] = g0b;
        lm[lr * 16 + wv * 4 + 2] = g1a;
        lm[lr * 16 + wv * 4 + 3] = g1b;
      }
    }
    __syncthreads();
    {
      int lr = t >> 1, g = t & 1;
      ull c0 = lm[lr * 16 + 0 + g * 2], c1 = lm[lr * 16 + 0 + g * 2 + 1];
#pragma unroll
      for (int w2 = 1; w2 < 4; ++w2)
        merge2(c0, c1, lm[lr * 16 + w2 * 4 + g * 2], lm[lr * 16 + w2 * 4 + g * 2 + 1]);
      int row = m0 + lr;
      ulonglong2 v; v.x = c0; v.y = c1;
      *(ulonglong2*)&pcb[(size_t)row * 128 + (2 * I + g) * 2] = v;
    }
  }
}

// ---------------------------------------------------------------------------
// Kernel M: exact top-10 from candidates. One wave per row; lane = group
// (64 cols each), holds the group's sorted top-2. 10 butterfly-argmax rounds;
// on lane exhaustion the wave recomputes that group's 64 scores from x
// (bitwise-identical fmaf chain), filters key<mx (+orig-idx exclusion),
// top-2 reduces, refills. Exact (hidden 3rd < stored 2nd <= extracted mx).
// ---------------------------------------------------------------------------
__global__ __launch_bounds__(256) void merge_kernel(const float* __restrict__ x,
                                                    const float* __restrict__ xxg,
                                                    const ull* __restrict__ pcall,
                                                    int* __restrict__ idxout) {
  int t = threadIdx.x;
  int lane = t & 63;
  int wv = t >> 6;
  int bb = blockIdx.y;
  int row = blockIdx.x * 4 + wv;
  const ull* pr = pcall + ((size_t)bb * NDIM + row) * 128;
  ulonglong2 c = ((const ulonglong2*)pr)[lane];
  ull c1 = c.x, c2 = c.y;
  unsigned orig0 = (unsigned)(c1 & 0xFFFFFFFFull);
  unsigned orig1 = (unsigned)(c2 & 0xFFFFFFFFull);

  const float* xb = x + (size_t)bb * CDIM * NDIM;
  const float* xxb = xxg + (size_t)bb * NDIM;

  // stage this row's x column (x[c][row], c=0..127) for rescan reuse
  __shared__ float xrow_s[4 * 128];
  xrow_s[wv * 128 + lane] = xb[(size_t)lane * NDIM + row];
  xrow_s[wv * 128 + 64 + lane] = xb[(size_t)(64 + lane) * NDIM + row];

  int my = 0;
  for (int s = 0; s < KSEL; ++s) {
    ull mx = c1;
#pragma unroll
    for (int off = 1; off < 64; off <<= 1) {
      ull o = __shfl_xor(mx, off);
      mx = o > mx ? o : mx;
    }
    if (lane == s) my = 4095 - (int)(unsigned)(mx & 0xFFFFFFFFull);
    if (s < KSEL - 1) {
      bool iswin = (c1 == mx);
      ull bal = __ballot(iswin && (c2 == 0ull));
      if (iswin) { c1 = c2; c2 = 0ull; }
      if (bal) {
        int g = (int)(__ffsll((long long)bal) - 1);
        unsigned e0 = __shfl(orig0, g), e1 = __shfl(orig1, g);
        int col = g * 64 + lane;
        const float* xc = xb + col;
        const float* xrs = xrow_s + wv * 128;
        float d = 0.f;
        for (int cc = 0; cc < 128; ++cc)
          d = __builtin_fmaf(xc[(size_t)cc * NDIM], xrs[cc], d);
        float sv = __builtin_fmaf(2.f, d, -xxb[col]);
        unsigned low = 4095u - (unsigned)col;
        ull key = makekey(sv, low);
        if (key >= mx || low == e0 || low == e1) key = 0ull;
        ull r1 = key;
#pragma unroll
        for (int off = 1; off < 64; off <<= 1) {
          ull o = __shfl_xor(r1, off);
          r1 = o > r1 ? o : r1;
        }
        ull key2 = (key == r1) ? 0ull : key;
        ull r2 = key2;
#pragma unroll
        for (int off = 1; off < 64; off <<= 1) {
          ull o = __shfl_xor(r2, off);
          r2 = o > r2 ? o : r2;
        }
        if (lane == g) { c1 = r1; c2 = r2; }
      }
    }
  }
  if (lane < KSEL)
    idxout[((size_t)bb * NDIM + row) * KSEL + lane] = my;
}

// ---------------------------------------------------------------------------
// Kernel C: Md[b][c][n] = mean_k x[b][c][idx[b][n][k]] - x[b][c][n]
// ---------------------------------------------------------------------------
__global__ __launch_bounds__(256) void gather_kernel(const float* __restrict__ x,
                                                     const int* __restrict__ idxg,
                                                     float* __restrict__ Md) {
  const int N = NDIM;
  int bb = blockIdx.y, c = blockIdx.x;
  __shared__ float row_s[NDIM];
  const float* rowg = x + (size_t)(bb * CDIM + c) * N;
  int t = threadIdx.x;
#pragma unroll
  for (int p = 0; p < 4; ++p) {
    int i4 = t + 256 * p;
    *(float4*)&row_s[i4 * 4] = *(const float4*)&rowg[i4 * 4];
  }
  __syncthreads();
  float* outp = Md + (size_t)(bb * CDIM + c) * N;
  const int* ib = idxg + (size_t)bb * N * KSEL;
  for (int p = 0; p < 16; ++p) {
    int n = t + 256 * p;
    const int* ip = ib + (size_t)n * KSEL;
    float s = 0.f;
#pragma unroll
    for (int k = 0; k < KSEL; ++k) s += row_s[ip[k]];
    outp[n] = s * 0.1f - row_s[n];
  }
}

// ---------------------------------------------------------------------------
// Kernel D: out via pre-transposed WT. T3 2-phase double-buffered staging
// (sync -> stage(next) -> compute(cur)); 48 KB LDS.
// ---------------------------------------------------------------------------
__global__ __launch_bounds__(256) void out_kernel(const float* __restrict__ Md,
                                                  const float* __restrict__ x,
                                                  const float* __restrict__ WT,
                                                  const float* __restrict__ bias,
                                                  float* __restrict__ out) {
  const int N = NDIM, O = 256;
  int bb = blockIdx.z;
  int o0 = blockIdx.y * 64;
  int n0 = blockIdx.x * 128;
  int t = threadIdx.x;
  int tx = t & 15, ty = t >> 4;
  int tx4 = tx * 4, ty4 = ty * 4;

  // 2 buffers x (wt[32][64]=2048 + src[32][128]=4096) = 12288 floats = 48 KB
  __shared__ float smem[12288];

  float acc[4][8];
#pragma unroll
  for (int i = 0; i < 4; ++i)
#pragma unroll
    for (int j = 0; j < 8; ++j) acc[i][j] = 0.f;

  auto stage = [&](float* buf, int ch) {
    const float* src = (ch < 4)
        ? Md + (size_t)(bb * CDIM + ch * 32) * N
        : x + (size_t)(bb * CDIM + (ch - 4) * 32) * N;
    float* wt_s = buf;
    float* src_s = buf + 2048;
#pragma unroll
    for (int p = 0; p < 2; ++p) {
      int i4 = t + 256 * p;
      async_cp16(&wt_s[i4 * 4], &WT[(size_t)(ch * 32 + (i4 >> 4)) * O + o0 + (i4 & 15) * 4]);
    }
#pragma unroll
    for (int p = 0; p < 4; ++p) {
      int i4 = t + 256 * p;
      async_cp16(&src_s[i4 * 4], &src[(size_t)(i4 >> 5) * N + n0 + (i4 & 31) * 4]);
    }
  };

  stage(smem, 0);  // prologue prefetch

  for (int ch = 0; ch < 8; ++ch) {
    __syncthreads();
    float* cur = smem + (ch & 1) * 6144;
    if (ch < 7) stage(smem + ((ch + 1) & 1) * 6144, ch + 1);

    float* wt_s = cur;
    float* src_s = cur + 2048;
#pragma unroll 4
    for (int cc = 0; cc < 32; ++cc) {
      float4 a = *(const float4*)&wt_s[cc * 64 + ty4];
      float4 b0 = *(const float4*)&src_s[cc * 128 + tx4];
      float4 b1 = *(const float4*)&src_s[cc * 128 + tx4 + 64];
      float av[4] = {a.x, a.y, a.z, a.w};
      float bv[8] = {b0.x, b0.y, b0.z, b0.w, b1.x, b1.y, b1.z, b1.w};
#pragma unroll
      for (int i = 0; i < 4; ++i)
#pragma unroll
        for (int j = 0; j < 8; ++j) acc[i][j] += av[i] * bv[j];
    }
  }

#pragma unroll
  for (int i = 0; i < 4; ++i) {
    int o = o0 + ty4 + i;
    float bv = bias[o];
    float* po = out + (size_t)(bb * O + o) * N + n0;
    *(float4*)&po[tx4] = make_float4(acc[i][0] + bv, acc[i][1] + bv,
                                     acc[i][2] + bv, acc[i][3] + bv);
    *(float4*)&po[tx4 + 64] = make_float4(acc[i][4] + bv, acc[i][5] + bv,
                                          acc[i][6] + bv, acc[i][7] + bv);
  }
}

// ---------------------------------------------------------------------------
extern "C" void kernel_launch(void* const* d_in, const int* in_sizes, int n_in,
                              void* d_out, int out_size, void* d_ws, size_t ws_size,
                              hipStream_t stream) {
  const float* x = (const float*)d_in[0];     // (4,128,4096) fp32
  const float* W = (const float*)d_in[1];     // (256,256,1,1) fp32
  const float* bias = (const float*)d_in[2];  // (256,) fp32
  float* out = (float*)d_out;                 // (4,256,4096) fp32

  // ws carve: xx 64K | idx 640K | Md 8M | pc 4x4M | WT 256K at top
  float* xx = (float*)d_ws;
  int* idx = (int*)((char*)d_ws + 65536);
  float* Md = (float*)((char*)d_ws + 65536 + 655360);
  const size_t fixed = 9109504;
  ull* pc = (ull*)((char*)d_ws + fixed);      // 4 batches x 4096x128 u64 = 16 MB
  size_t wt_off = (ws_size - 262144) & ~(size_t)255;
  float* WT = (float*)((char*)d_ws + wt_off);

  xx_kernel<<<dim3(256), 256, 0, stream>>>(x, xx);
  wtrans_kernel<<<dim3(256), 256, 0, stream>>>(W, WT);
  score_kernel<<<dim3(528, 4), 256, 0, stream>>>(x, xx, pc);
  merge_kernel<<<dim3(1024, 4), 256, 0, stream>>>(x, xx, pc, idx);
  gather_kernel<<<dim3(128, 4), 256, 0, stream>>>(x, idx, Md);
  out_kernel<<<dim3(32, 4, 4), 256, 0, stream>>>(Md, x, WT, bias, out);
}

// Round 4
// 283.106 us; speedup vs baseline: 1.0355x; 1.0355x over previous
//
#include <hip/hip_runtime.h>
#include <stdint.h>

#define BDIM 4
#define CDIM 128
#define NDIM 4096
#define KSEL 10

typedef unsigned long long ull;

// CK-style global->LDS direct copy (16 B/lane).
__device__ __forceinline__ void async_cp16(void* lds, const void* g) {
  auto* gp = (const __attribute__((address_space(1))) unsigned int*)(uintptr_t)g;
  auto* lp = (__attribute__((address_space(3))) unsigned int*)(unsigned int)(uintptr_t)lds;
  __builtin_amdgcn_global_load_lds(gp, lp, 16, 0, 0);
}

__device__ __forceinline__ ull umax64(ull a, ull b) { return a > b ? a : b; }
__device__ __forceinline__ ull umin64(ull a, ull b) { return a > b ? b : a; }

// merge two sorted-desc pairs (a0>=a1),(b0>=b1) -> sorted top-2 of union
__device__ __forceinline__ void merge2(ull& a0, ull& a1, ull b0, ull b1) {
  ull c0 = umax64(a0, b0);
  ull c1 = umax64(umin64(a0, b0), umax64(a1, b1));
  a0 = c0; a1 = c1;
}

__device__ __forceinline__ ull makekey(float s, unsigned low) {
  unsigned u = __float_as_uint(s);
  unsigned mono = u ^ ((unsigned)(((int)u) >> 31) | 0x80000000u);
  return ((ull)mono << 32) | (ull)low;
}

// ---------------------------------------------------------------------------
// Kernel A: xx[b][n] = sum_c x[b][c][n]^2
// ---------------------------------------------------------------------------
__global__ __launch_bounds__(256) void xx_kernel(const float* __restrict__ x,
                                                 float* __restrict__ xx) {
  int t = threadIdx.x;
  int nl = t >> 2;
  int part = t & 3;
  int g = blockIdx.x * 64 + nl;
  int b = g >> 12;
  int n = g & (NDIM - 1);
  const float* xp = x + (size_t)b * CDIM * NDIM + n;
  float s = 0.f;
  int c0 = part * 32;
#pragma unroll
  for (int i = 0; i < 32; ++i) {
    float v = xp[(size_t)(c0 + i) * NDIM];
    s += v * v;
  }
  s += __shfl_xor(s, 1, 4);
  s += __shfl_xor(s, 2, 4);
  if (part == 0) xx[g] = s;
}

// ---------------------------------------------------------------------------
// Kernel W: WT[c][o] = W[o][c]
// ---------------------------------------------------------------------------
__global__ __launch_bounds__(256) void wtrans_kernel(const float* __restrict__ W,
                                                     float* __restrict__ WT) {
  int c = blockIdx.x, o = threadIdx.x;
  WT[c * 256 + o] = W[o * 256 + c];
}

// ---------------------------------------------------------------------------
// Kernel S: score GEMM (symmetry-halved) -> per-(row, 64-col-group) top-2
// candidate keys. Key = mono(score)<<32 | (4095-m): exact (val desc, idx asc).
// R12: epilogue restructure. The R9/R10 shfl_xor butterflies burned
// ~256 ds_bpermute + ~1800 VALU per thread in serial chains (all 16 lanes
// computing redundantly, 1 lane using the result). Replaced with
// scatter-to-LDS + tree-reduce: each lane writes its per-lane sorted top-2
// pair, 1 thread per (row,group) merges 16 pairs. merge2 on distinct keys is
// merge-order independent -> result bit-identical to butterfly.
// LDS scratch: 64 rows x 2 groups x 16 slots x ulonglong2 = 32 KB per half,
// 2 half-passes per side. Slots XOR-swizzled (slot = src ^ ((pair>>1)&15))
// so write+reduce phases hit 8 distinct addrs/bank (optimal b128 spread).
// GEMM loop = R10 exact (dbuf, unroll 4); numerics bit-identical throughout.
// ---------------------------------------------------------------------------
__global__ __launch_bounds__(256) void score_kernel(const float* __restrict__ x,
                                                    const float* __restrict__ xxg,
                                                    ull* __restrict__ pcall) {
  const int N = NDIM;
  int bb = blockIdx.y;
  ull* pcb = pcall + (size_t)bb * N * 128;
  int p = blockIdx.x;
  int I = 0;
  while (p >= 32 - I) { p -= 32 - I; ++I; }
  int J = I + p;
  int n0 = I * 128, m0 = J * 128;

  int t = threadIdx.x;
  int tx = t & 15, ty = t >> 4;
  int tx4 = tx * 4, ty4 = ty * 4;

  // 2 buffers x (xn[16][128] + xm[16][128]) = 8192 floats = 32 KB.
  // Reused as top-2 reduce scratch (exactly 32 KB) after the GEMM.
  __shared__ __align__(16) float smem[8192];

  const float* xb = x + (size_t)bb * CDIM * N;

  float acc[8][8];
#pragma unroll
  for (int i = 0; i < 8; ++i)
#pragma unroll
    for (int j = 0; j < 8; ++j) acc[i][j] = 0.f;

  // stage 16-channel chunk ch into buffer buf (xn at buf, xm at buf+2048)
  auto stage = [&](float* buf, int ch) {
    int c0 = ch * 16;
#pragma unroll
    for (int pp = 0; pp < 2; ++pp) {
      int i4 = t + 256 * pp;
      async_cp16(&buf[i4 * 4], &xb[(size_t)(c0 + (i4 >> 5)) * N + n0 + (i4 & 31) * 4]);
    }
#pragma unroll
    for (int pp = 0; pp < 2; ++pp) {
      int i4 = t + 256 * pp;
      async_cp16(&buf[2048 + i4 * 4], &xb[(size_t)(c0 + (i4 >> 5)) * N + m0 + (i4 & 31) * 4]);
    }
  };

  stage(smem, 0);  // prologue prefetch (chunk 0 -> buf 0)

  for (int ch = 0; ch < 8; ++ch) {
    __syncthreads();
    float* cur = smem + (ch & 1) * 4096;
    if (ch < 7) stage(smem + ((ch + 1) & 1) * 4096, ch + 1);

    float* xn_s = cur;
    float* xm_s = cur + 2048;
#pragma unroll 4
    for (int cc = 0; cc < 16; ++cc) {
      float4 a0 = *(const float4*)&xn_s[cc * 128 + ty4];
      float4 a1 = *(const float4*)&xn_s[cc * 128 + ty4 + 64];
      float4 b0 = *(const float4*)&xm_s[cc * 128 + tx4];
      float4 b1 = *(const float4*)&xm_s[cc * 128 + tx4 + 64];
      float av[8] = {a0.x, a0.y, a0.z, a0.w, a1.x, a1.y, a1.z, a1.w};
      float bv[8] = {b0.x, b0.y, b0.z, b0.w, b1.x, b1.y, b1.z, b1.w};
#pragma unroll
      for (int i = 0; i < 8; ++i)
#pragma unroll
        for (int j = 0; j < 8; ++j) acc[i][j] += av[i] * bv[j];
    }
  }

  const float* xxb = xxg + (size_t)bb * N;
  ulonglong2* lds2 = (ulonglong2*)smem;  // [pair 128][slot 16] ulonglong2

  // ----- n-side: rows n0.., groups 2J,2J+1 -----
  {
    float4 w0 = *(const float4*)&xxb[m0 + tx4];
    float4 w1 = *(const float4*)&xxb[m0 + tx4 + 64];
    float xv[8] = {w0.x, w0.y, w0.z, w0.w, w1.x, w1.y, w1.z, w1.w};
    unsigned mlow[8];
#pragma unroll
    for (int j = 0; j < 8; ++j)
      mlow[j] = 4095u - (unsigned)(m0 + tx4 + (j & 3) + (j >> 2) * 64);

#pragma unroll
    for (int h = 0; h < 2; ++h) {
      __syncthreads();  // prior smem users (GEMM / previous reduce) done
#pragma unroll
      for (int ii = 0; ii < 4; ++ii) {
        int i = h * 4 + ii;
        ull k[8];
#pragma unroll
        for (int j = 0; j < 8; ++j)
          k[j] = makekey(__builtin_fmaf(2.f, acc[i][j], -xv[j]), mlow[j]);
        ull g0a = umax64(k[0], k[1]), g0b = umin64(k[0], k[1]);
        merge2(g0a, g0b, umax64(k[2], k[3]), umin64(k[2], k[3]));
        ull g1a = umax64(k[4], k[5]), g1b = umin64(k[4], k[5]);
        merge2(g1a, g1b, umax64(k[6], k[7]), umin64(k[6], k[7]));
        int r = ty4 + ii;        // local row 0..63
        int p0 = r * 2;          // pair for group 2J
        int p1 = r * 2 + 1;      // pair for group 2J+1
        ulonglong2 v0; v0.x = g0a; v0.y = g0b;
        ulonglong2 v1; v1.x = g1a; v1.y = g1b;
        lds2[p0 * 16 + (tx ^ ((p0 >> 1) & 15))] = v0;
        lds2[p1 * 16 + (tx ^ ((p1 >> 1) & 15))] = v1;
      }
      __syncthreads();
      if (t < 128) {
        int pair = t;
        int r = pair >> 1, g = pair & 1;
        int kx = (pair >> 1) & 15;
        ulonglong2 e0 = lds2[pair * 16 + (0 ^ kx)];
        ull c0 = e0.x, c1 = e0.y;
#pragma unroll
        for (int e = 1; e < 16; ++e) {
          ulonglong2 ev = lds2[pair * 16 + (e ^ kx)];
          merge2(c0, c1, ev.x, ev.y);
        }
        int row = n0 + h * 64 + r;
        ulonglong2 v; v.x = c0; v.y = c1;
        *(ulonglong2*)&pcb[(size_t)row * 128 + (2 * J + g) * 2] = v;
      }
    }
  }

  // ----- m-side (off-diag): rows m0.., groups 2I,2I+1 -----
  if (J != I) {
    float4 u0 = *(const float4*)&xxb[n0 + ty4];
    float4 u1 = *(const float4*)&xxb[n0 + ty4 + 64];
    float uv[8] = {u0.x, u0.y, u0.z, u0.w, u1.x, u1.y, u1.z, u1.w};
    unsigned nlow[8];
#pragma unroll
    for (int i = 0; i < 8; ++i)
      nlow[i] = 4095u - (unsigned)(n0 + ty4 + (i & 3) + (i >> 2) * 64);

#pragma unroll
    for (int h = 0; h < 2; ++h) {
      __syncthreads();  // n-side (or previous half) reduce reads done
#pragma unroll
      for (int jj = 0; jj < 4; ++jj) {
        int j = h * 4 + jj;
        ull k[8];
#pragma unroll
        for (int i = 0; i < 8; ++i)
          k[i] = makekey(__builtin_fmaf(2.f, acc[i][j], -uv[i]), nlow[i]);
        ull g0a = umax64(k[0], k[1]), g0b = umin64(k[0], k[1]);
        merge2(g0a, g0b, umax64(k[2], k[3]), umin64(k[2], k[3]));
        ull g1a = umax64(k[4], k[5]), g1b = umin64(k[4], k[5]);
        merge2(g1a, g1b, umax64(k[6], k[7]), umin64(k[6], k[7]));
        int cl = tx4 + jj;       // local col 0..63
        int p0 = cl * 2;         // pair for group 2I
        int p1 = cl * 2 + 1;     // pair for group 2I+1
        ulonglong2 v0; v0.x = g0a; v0.y = g0b;
        ulonglong2 v1; v1.x = g1a; v1.y = g1b;
        lds2[p0 * 16 + (ty ^ ((p0 >> 1) & 15))] = v0;
        lds2[p1 * 16 + (ty ^ ((p1 >> 1) & 15))] = v1;
      }
      __syncthreads();
      if (t < 128) {
        int pair = t;
        int cl = pair >> 1, ng = pair & 1;
        int kx = (pair >> 1) & 15;
        ulonglong2 e0 = lds2[pair * 16 + (0 ^ kx)];
        ull c0 = e0.x, c1 = e0.y;
#pragma unroll
        for (int e = 1; e < 16; ++e) {
          ulonglong2 ev = lds2[pair * 16 + (e ^ kx)];
          merge2(c0, c1, ev.x, ev.y);
        }
        int row = m0 + h * 64 + cl;
        ulonglong2 v; v.x = c0; v.y = c1;
        *(ulonglong2*)&pcb[(size_t)row * 128 + (2 * I + ng) * 2] = v;
      }
    }
  }
}

// ---------------------------------------------------------------------------
// Kernel M: exact top-10 from candidates. One wave per row; lane = group
// (64 cols each), holds the group's sorted top-2. 10 butterfly-argmax rounds;
// on lane exhaustion the wave recomputes that group's 64 scores from x
// (bitwise-identical fmaf chain), filters key<mx (+orig-idx exclusion),
// top-2 reduces, refills. Exact (hidden 3rd < stored 2nd <= extracted mx).
// ---------------------------------------------------------------------------
__global__ __launch_bounds__(256) void merge_kernel(const float* __restrict__ x,
                                                    const float* __restrict__ xxg,
                                                    const ull* __restrict__ pcall,
                                                    int* __restrict__ idxout) {
  int t = threadIdx.x;
  int lane = t & 63;
  int wv = t >> 6;
  int bb = blockIdx.y;
  int row = blockIdx.x * 4 + wv;
  const ull* pr = pcall + ((size_t)bb * NDIM + row) * 128;
  ulonglong2 c = ((const ulonglong2*)pr)[lane];
  ull c1 = c.x, c2 = c.y;
  unsigned orig0 = (unsigned)(c1 & 0xFFFFFFFFull);
  unsigned orig1 = (unsigned)(c2 & 0xFFFFFFFFull);

  const float* xb = x + (size_t)bb * CDIM * NDIM;
  const float* xxb = xxg + (size_t)bb * NDIM;

  // stage this row's x column (x[c][row], c=0..127) for rescan reuse
  __shared__ float xrow_s[4 * 128];
  xrow_s[wv * 128 + lane] = xb[(size_t)lane * NDIM + row];
  xrow_s[wv * 128 + 64 + lane] = xb[(size_t)(64 + lane) * NDIM + row];

  int my = 0;
  for (int s = 0; s < KSEL; ++s) {
    ull mx = c1;
#pragma unroll
    for (int off = 1; off < 64; off <<= 1) {
      ull o = __shfl_xor(mx, off);
      mx = o > mx ? o : mx;
    }
    if (lane == s) my = 4095 - (int)(unsigned)(mx & 0xFFFFFFFFull);
    if (s < KSEL - 1) {
      bool iswin = (c1 == mx);
      ull bal = __ballot(iswin && (c2 == 0ull));
      if (iswin) { c1 = c2; c2 = 0ull; }
      if (bal) {
        int g = (int)(__ffsll((long long)bal) - 1);
        unsigned e0 = __shfl(orig0, g), e1 = __shfl(orig1, g);
        int col = g * 64 + lane;
        const float* xc = xb + col;
        const float* xrs = xrow_s + wv * 128;
        float d = 0.f;
        for (int cc = 0; cc < 128; ++cc)
          d = __builtin_fmaf(xc[(size_t)cc * NDIM], xrs[cc], d);
        float sv = __builtin_fmaf(2.f, d, -xxb[col]);
        unsigned low = 4095u - (unsigned)col;
        ull key = makekey(sv, low);
        if (key >= mx || low == e0 || low == e1) key = 0ull;
        ull r1 = key;
#pragma unroll
        for (int off = 1; off < 64; off <<= 1) {
          ull o = __shfl_xor(r1, off);
          r1 = o > r1 ? o : r1;
        }
        ull key2 = (key == r1) ? 0ull : key;
        ull r2 = key2;
#pragma unroll
        for (int off = 1; off < 64; off <<= 1) {
          ull o = __shfl_xor(r2, off);
          r2 = o > r2 ? o : r2;
        }
        if (lane == g) { c1 = r1; c2 = r2; }
      }
    }
  }
  if (lane < KSEL)
    idxout[((size_t)bb * NDIM + row) * KSEL + lane] = my;
}

// ---------------------------------------------------------------------------
// Kernel C: Md[b][c][n] = mean_k x[b][c][idx[b][n][k]] - x[b][c][n]
// ---------------------------------------------------------------------------
__global__ __launch_bounds__(256) void gather_kernel(const float* __restrict__ x,
                                                     const int* __restrict__ idxg,
                                                     float* __restrict__ Md) {
  const int N = NDIM;
  int bb = blockIdx.y, c = blockIdx.x;
  __shared__ float row_s[NDIM];
  const float* rowg = x + (size_t)(bb * CDIM + c) * N;
  int t = threadIdx.x;
#pragma unroll
  for (int p = 0; p < 4; ++p) {
    int i4 = t + 256 * p;
    *(float4*)&row_s[i4 * 4] = *(const float4*)&rowg[i4 * 4];
  }
  __syncthreads();
  float* outp = Md + (size_t)(bb * CDIM + c) * N;
  const int* ib = idxg + (size_t)bb * N * KSEL;
  for (int p = 0; p < 16; ++p) {
    int n = t + 256 * p;
    const int* ip = ib + (size_t)n * KSEL;
    float s = 0.f;
#pragma unroll
    for (int k = 0; k < KSEL; ++k) s += row_s[ip[k]];
    outp[n] = s * 0.1f - row_s[n];
  }
}

// ---------------------------------------------------------------------------
// Kernel D: out via pre-transposed WT. T3 2-phase double-buffered staging
// (sync -> stage(next) -> compute(cur)); 48 KB LDS.
// ---------------------------------------------------------------------------
__global__ __launch_bounds__(256) void out_kernel(const float* __restrict__ Md,
                                                  const float* __restrict__ x,
                                                  const float* __restrict__ WT,
                                                  const float* __restrict__ bias,
                                                  float* __restrict__ out) {
  const int N = NDIM, O = 256;
  int bb = blockIdx.z;
  int o0 = blockIdx.y * 64;
  int n0 = blockIdx.x * 128;
  int t = threadIdx.x;
  int tx = t & 15, ty = t >> 4;
  int tx4 = tx * 4, ty4 = ty * 4;

  // 2 buffers x (wt[32][64]=2048 + src[32][128]=4096) = 12288 floats = 48 KB
  __shared__ float smem[12288];

  float acc[4][8];
#pragma unroll
  for (int i = 0; i < 4; ++i)
#pragma unroll
    for (int j = 0; j < 8; ++j) acc[i][j] = 0.f;

  auto stage = [&](float* buf, int ch) {
    const float* src = (ch < 4)
        ? Md + (size_t)(bb * CDIM + ch * 32) * N
        : x + (size_t)(bb * CDIM + (ch - 4) * 32) * N;
    float* wt_s = buf;
    float* src_s = buf + 2048;
#pragma unroll
    for (int p = 0; p < 2; ++p) {
      int i4 = t + 256 * p;
      async_cp16(&wt_s[i4 * 4], &WT[(size_t)(ch * 32 + (i4 >> 4)) * O + o0 + (i4 & 15) * 4]);
    }
#pragma unroll
    for (int p = 0; p < 4; ++p) {
      int i4 = t + 256 * p;
      async_cp16(&src_s[i4 * 4], &src[(size_t)(i4 >> 5) * N + n0 + (i4 & 31) * 4]);
    }
  };

  stage(smem, 0);  // prologue prefetch

  for (int ch = 0; ch < 8; ++ch) {
    __syncthreads();
    float* cur = smem + (ch & 1) * 6144;
    if (ch < 7) stage(smem + ((ch + 1) & 1) * 6144, ch + 1);

    float* wt_s = cur;
    float* src_s = cur + 2048;
#pragma unroll 4
    for (int cc = 0; cc < 32; ++cc) {
      float4 a = *(const float4*)&wt_s[cc * 64 + ty4];
      float4 b0 = *(const float4*)&src_s[cc * 128 + tx4];
      float4 b1 = *(const float4*)&src_s[cc * 128 + tx4 + 64];
      float av[4] = {a.x, a.y, a.z, a.w};
      float bv[8] = {b0.x, b0.y, b0.z, b0.w, b1.x, b1.y, b1.z, b1.w};
#pragma unroll
      for (int i = 0; i < 4; ++i)
#pragma unroll
        for (int j = 0; j < 8; ++j) acc[i][j] += av[i] * bv[j];
    }
  }

#pragma unroll
  for (int i = 0; i < 4; ++i) {
    int o = o0 + ty4 + i;
    float bv = bias[o];
    float* po = out + (size_t)(bb * O + o) * N + n0;
    *(float4*)&po[tx4] = make_float4(acc[i][0] + bv, acc[i][1] + bv,
                                     acc[i][2] + bv, acc[i][3] + bv);
    *(float4*)&po[tx4 + 64] = make_float4(acc[i][4] + bv, acc[i][5] + bv,
                                          acc[i][6] + bv, acc[i][7] + bv);
  }
}

// ---------------------------------------------------------------------------
extern "C" void kernel_launch(void* const* d_in, const int* in_sizes, int n_in,
                              void* d_out, int out_size, void* d_ws, size_t ws_size,
                              hipStream_t stream) {
  const float* x = (const float*)d_in[0];     // (4,128,4096) fp32
  const float* W = (const float*)d_in[1];     // (256,256,1,1) fp32
  const float* bias = (const float*)d_in[2];  // (256,) fp32
  float* out = (float*)d_out;                 // (4,256,4096) fp32

  // ws carve: xx 64K | idx 640K | Md 8M | pc 4x4M | WT 256K at top
  float* xx = (float*)d_ws;
  int* idx = (int*)((char*)d_ws + 65536);
  float* Md = (float*)((char*)d_ws + 65536 + 655360);
  const size_t fixed = 9109504;
  ull* pc = (ull*)((char*)d_ws + fixed);      // 4 batches x 4096x128 u64 = 16 MB
  size_t wt_off = (ws_size - 262144) & ~(size_t)255;
  float* WT = (float*)((char*)d_ws + wt_off);

  xx_kernel<<<dim3(256), 256, 0, stream>>>(x, xx);
  wtrans_kernel<<<dim3(256), 256, 0, stream>>>(W, WT);
  score_kernel<<<dim3(528, 4), 256, 0, stream>>>(x, xx, pc);
  merge_kernel<<<dim3(1024, 4), 256, 0, stream>>>(x, xx, pc, idx);
  gather_kernel<<<dim3(128, 4), 256, 0, stream>>>(x, idx, Md);
  out_kernel<<<dim3(32, 4, 4), 256, 0, stream>>>(Md, x, WT, bias, out);
}